// Round 12
// baseline (373.381 us; speedup 1.0000x reference)
//
#include <hip/hip_runtime.h>
#include <math.h>

#define NN 150000      // nodes (== 16 * 9375)
#define NE 4800000     // edges (without self loops)
#define HD 16          // hidden dim
#define NBUCK 586      // ceil(NN/256) buckets of 256 nodes
#define BSH 8
#define NBLK 256       // partition chunks
#define CHUNK 18750    // NE / NBLK (exact)
#define NSCAN 150016   // NBUCK * NBLK
#define SCANB 147      // ceil(NSCAN / 1024)
#define PL ((size_t)NN * 8)   // elements per 8-feature plane

// ---- bf16 helpers (bit-level, round-to-nearest-even) ----
__device__ __forceinline__ float bf2f(unsigned short u) {
    return __uint_as_float(((unsigned int)u) << 16);
}
__device__ __forceinline__ unsigned short f2bf(float f) {
    unsigned int x = __float_as_uint(f);
    return (unsigned short)((x + 0x7FFFu + ((x >> 16) & 1u)) >> 16);
}

// ================= phase A: partition edges into 586 dst-buckets =================

__global__ __launch_bounds__(512) void k_part_count(const int* __restrict__ dst,
                                                    int* __restrict__ C) {
    __shared__ int h[NBUCK];
    for (int i = threadIdx.x; i < NBUCK; i += 512) h[i] = 0;
    __syncthreads();
    int base = blockIdx.x * CHUNK;
    for (int i = threadIdx.x; i < CHUNK; i += 512)
        atomicAdd(&h[dst[base + i] >> BSH], 1);
    __syncthreads();
    for (int i = threadIdx.x; i < NBUCK; i += 512) C[i * NBLK + blockIdx.x] = h[i];
}

__global__ void k_scanA(int* __restrict__ C, int* __restrict__ psum) {
    __shared__ int s[1024];
    int t = threadIdx.x;
    int i = blockIdx.x * 1024 + t;
    int v = (i < NSCAN) ? C[i] : 0;
    s[t] = v;
    __syncthreads();
    for (int off = 1; off < 1024; off <<= 1) {
        int x = (t >= off) ? s[t - off] : 0;
        __syncthreads();
        s[t] += x;
        __syncthreads();
    }
    if (i < NSCAN) C[i] = s[t] - v;       // local exclusive
    if (t == 1023) psum[blockIdx.x] = s[1023];
}

__global__ void k_scanB(int* __restrict__ psum) {
    __shared__ int s[512];
    int t = threadIdx.x;
    int v = (t < SCANB) ? psum[t] : 0;
    s[t] = v;
    __syncthreads();
    for (int off = 1; off < 512; off <<= 1) {
        int x = (t >= off) ? s[t - off] : 0;
        __syncthreads();
        s[t] += x;
        __syncthreads();
    }
    if (t < SCANB) psum[t] = s[t] - v;    // exclusive
}

__global__ void k_scanC(int* __restrict__ C, const int* __restrict__ psum,
                        int* __restrict__ bstart) {
    int i = blockIdx.x * 1024 + threadIdx.x;
    if (i >= NSCAN) return;
    int v = C[i] + psum[blockIdx.x];
    C[i] = v;
    if ((i & (NBLK - 1)) == 0) bstart[i >> BSH] = v;   // (b, chunk=0) -> bucket base
    if (i == 0) bstart[NBUCK] = NE;
}

// scatter edges into bucket-grouped packed array (unchanged control vs r11)
__global__ __launch_bounds__(512) void k_part_scatter(const int* __restrict__ src,
                                                      const int* __restrict__ dst,
                                                      const int* __restrict__ C,
                                                      int* __restrict__ packed) {
    __shared__ int cur[NBUCK];
    int bid = blockIdx.x;
    int m = ((bid & 7) << 5) | (bid >> 3);   // bijective on [0,256)
    for (int i = threadIdx.x; i < NBUCK; i += 512) cur[i] = C[i * NBLK + m];
    __syncthreads();
    int base = m * CHUNK;
    for (int i = threadIdx.x; i < CHUNK; i += 512) {
        int s = src[base + i], d = dst[base + i];
        int pos = atomicAdd(&cur[d >> BSH], 1);
        packed[pos] = (s << BSH) | (d & 255);   // src < 2^18, local dst < 2^8
    }
}

// ================= phase B: per-bucket local counting sort =================
__global__ __launch_bounds__(256) void k_bucket_sort(const int* __restrict__ packed,
                                                     const int* __restrict__ bstart,
                                                     int* __restrict__ row_start,
                                                     float* __restrict__ dinv,
                                                     int* __restrict__ ssrc) {
    __shared__ int hist[256];
    __shared__ int fill[256];
    int b = blockIdx.x;
    int t = threadIdx.x;
    int v0 = b << BSH;
    int nv = min(256, NN - v0);
    int e0 = bstart[b], e1 = bstart[b + 1];
    hist[t] = 0;
    __syncthreads();
    for (int e = e0 + t; e < e1; e += 256)
        atomicAdd(&hist[packed[e] & 255], 1);
    __syncthreads();
    int cv = hist[t];
    __syncthreads();
    for (int off = 1; off < 256; off <<= 1) {
        int x = (t >= off) ? hist[t - off] : 0;
        __syncthreads();
        hist[t] += x;
        __syncthreads();
    }
    int excl = hist[t] - cv;
    if (t < nv) {
        row_start[v0 + t] = e0 + excl;
        fill[t] = e0 + excl;
        dinv[v0 + t] = rsqrtf((float)cv + 1.0f);   // +1: self loop
    }
    __syncthreads();
    for (int e = e0 + t; e < e1; e += 256) {
        int p = packed[e];
        int pos = atomicAdd(&fill[p & 255], 1);
        ssrc[pos] = p >> BSH;
    }
    if (b == 0 && t == 0) row_start[NN] = NE;
}

// ====== layer 1 transform: t = (x @ W_in) * dinv, written as TWO 8-feat planes ======
__global__ __launch_bounds__(256) void k_transform_in(const float* __restrict__ x,
                                                      const float* __restrict__ W,
                                                      const float* __restrict__ dinv,
                                                      unsigned short* __restrict__ tA) {
    int gid = blockIdx.x * blockDim.x + threadIdx.x;
    if (gid >= NN * HD) return;
    int v = gid >> 4, j = gid & 15;
    float s = x[v * 3 + 0] * W[j] + x[v * 3 + 1] * W[HD + j] + x[v * 3 + 2] * W[2 * HD + j];
    tA[(size_t)(j >> 3) * PL + (size_t)v * 8 + (j & 7)] = f2bf(s * dinv[v]);
}

// ====== generic plane gather: sums[v][0:8] = sum over neighbors of plane[src][0:8] ======
// 32 lanes/node: 8 edge slots (sub) x 4 feature-pair lanes (fl). Plane row = 16 B,
// L2-resident (2.4 MB < 4 MB per-XCD L2). No self loop here (finish adds it).
__global__ __launch_bounds__(512) void k_gather_plane(const int* __restrict__ row_start,
                                                      const int* __restrict__ ssrc,
                                                      const unsigned short* __restrict__ plane,
                                                      float* __restrict__ sums) {
    int tid = threadIdx.x;
    int node = tid >> 5;            // 0..15
    int lane = tid & 31;
    int sub  = lane >> 2;           // 0..7 edge slot
    int fl   = lane & 3;            // feature pair: 2*fl, 2*fl+1
    int v = blockIdx.x * 16 + node;
    int e0 = row_start[v], e1 = row_start[v + 1];
    float sx = 0.0f, sy = 0.0f;
    int e = e0 + sub;
    for (; e + 8 < e1; e += 16) {   // slots e and e+8 both valid
        int sA = ssrc[e], sB = ssrc[e + 8];
        unsigned int wA = *(const unsigned int*)(plane + (size_t)sA * 8 + 2 * fl);
        unsigned int wB = *(const unsigned int*)(plane + (size_t)sB * 8 + 2 * fl);
        sx += bf2f((unsigned short)wA) + bf2f((unsigned short)wB);
        sy += bf2f((unsigned short)(wA >> 16)) + bf2f((unsigned short)(wB >> 16));
    }
    for (; e < e1; e += 8) {
        unsigned int w = *(const unsigned int*)(plane + (size_t)ssrc[e] * 8 + 2 * fl);
        sx += bf2f((unsigned short)w);
        sy += bf2f((unsigned short)(w >> 16));
    }
    // reduce over sub (lane bits 2,3,4)
    sx += __shfl_xor(sx, 4);  sx += __shfl_xor(sx, 8);  sx += __shfl_xor(sx, 16);
    sy += __shfl_xor(sy, 4);  sy += __shfl_xor(sy, 8);  sy += __shfl_xor(sy, 16);
    if (sub == 0) {
        sums[(size_t)v * 8 + 2 * fl]     = sx;
        sums[(size_t)v * 8 + 2 * fl + 1] = sy;
    }
}

// ====== finish layer 2: h = relu((sums + self)*dinv + b); tB = (h @ W)*dinv (planes) ======
__global__ __launch_bounds__(256) void k_mlp_mid(const float* __restrict__ sums0,
                                                 const float* __restrict__ sums1,
                                                 const unsigned short* __restrict__ tA,
                                                 const float* __restrict__ dinv,
                                                 const float* __restrict__ b,
                                                 const float* __restrict__ W,
                                                 unsigned short* __restrict__ tB) {
    __shared__ float sW[256];
    __shared__ float sb[16];
    int tid = threadIdx.x;
    sW[tid] = W[tid];
    if (tid < 16) sb[tid] = b[tid];
    __syncthreads();
    int v = blockIdx.x * 256 + tid;
    if (v >= NN) return;
    float di = dinv[v];
    float h[16];
    const float4* s0 = (const float4*)(sums0 + (size_t)v * 8);
    const float4* s1 = (const float4*)(sums1 + (size_t)v * 8);
    uint4 a0 = *(const uint4*)(tA + (size_t)v * 8);
    uint4 a1 = *(const uint4*)(tA + PL + (size_t)v * 8);
#pragma unroll
    for (int q = 0; q < 2; ++q) {
        float4 s = s0[q];
        unsigned int w0 = (&a0.x)[2 * q], w1 = (&a0.x)[2 * q + 1];
        h[4 * q + 0] = fmaxf((s.x + bf2f((unsigned short)w0))         * di + sb[4 * q + 0], 0.0f);
        h[4 * q + 1] = fmaxf((s.y + bf2f((unsigned short)(w0 >> 16))) * di + sb[4 * q + 1], 0.0f);
        h[4 * q + 2] = fmaxf((s.z + bf2f((unsigned short)w1))         * di + sb[4 * q + 2], 0.0f);
        h[4 * q + 3] = fmaxf((s.w + bf2f((unsigned short)(w1 >> 16))) * di + sb[4 * q + 3], 0.0f);
    }
#pragma unroll
    for (int q = 0; q < 2; ++q) {
        float4 s = s1[q];
        unsigned int w0 = (&a1.x)[2 * q], w1 = (&a1.x)[2 * q + 1];
        h[8 + 4 * q + 0] = fmaxf((s.x + bf2f((unsigned short)w0))         * di + sb[8 + 4 * q + 0], 0.0f);
        h[8 + 4 * q + 1] = fmaxf((s.y + bf2f((unsigned short)(w0 >> 16))) * di + sb[8 + 4 * q + 1], 0.0f);
        h[8 + 4 * q + 2] = fmaxf((s.z + bf2f((unsigned short)w1))         * di + sb[8 + 4 * q + 2], 0.0f);
        h[8 + 4 * q + 3] = fmaxf((s.w + bf2f((unsigned short)(w1 >> 16))) * di + sb[8 + 4 * q + 3], 0.0f);
    }
    uint4 o0, o1;
#pragma unroll
    for (int p = 0; p < 4; ++p) {           // output u32 slots for plane 0 (feats 2p,2p+1)
        float oa = 0.0f, ob = 0.0f;
#pragma unroll
        for (int k = 0; k < 16; ++k) {
            oa += h[k] * sW[k * 16 + 2 * p];
            ob += h[k] * sW[k * 16 + 2 * p + 1];
        }
        (&o0.x)[p] = (unsigned int)f2bf(oa * di) | ((unsigned int)f2bf(ob * di) << 16);
    }
#pragma unroll
    for (int p = 0; p < 4; ++p) {           // plane 1 (feats 8+2p, 8+2p+1)
        float oa = 0.0f, ob = 0.0f;
#pragma unroll
        for (int k = 0; k < 16; ++k) {
            oa += h[k] * sW[k * 16 + 8 + 2 * p];
            ob += h[k] * sW[k * 16 + 8 + 2 * p + 1];
        }
        (&o1.x)[p] = (unsigned int)f2bf(oa * di) | ((unsigned int)f2bf(ob * di) << 16);
    }
    *(uint4*)(tB + (size_t)v * 8)      = o0;
    *(uint4*)(tB + PL + (size_t)v * 8) = o1;
}

// ====== finish layer 3: h = relu((sums + self)*dinv + b); t3 = (h . Wout)*dinv ======
__global__ __launch_bounds__(256) void k_out_finish(const float* __restrict__ sums0,
                                                    const float* __restrict__ sums1,
                                                    const unsigned short* __restrict__ tB,
                                                    const float* __restrict__ dinv,
                                                    const float* __restrict__ b,
                                                    const float* __restrict__ Wout,
                                                    float* __restrict__ t3) {
    __shared__ float sW[16];
    __shared__ float sb[16];
    int tid = threadIdx.x;
    if (tid < 16) { sW[tid] = Wout[tid]; sb[tid] = b[tid]; }
    __syncthreads();
    int v = blockIdx.x * 256 + tid;
    if (v >= NN) return;
    float di = dinv[v];
    const float4* s0 = (const float4*)(sums0 + (size_t)v * 8);
    const float4* s1 = (const float4*)(sums1 + (size_t)v * 8);
    uint4 a0 = *(const uint4*)(tB + (size_t)v * 8);
    uint4 a1 = *(const uint4*)(tB + PL + (size_t)v * 8);
    float acc = 0.0f;
#pragma unroll
    for (int q = 0; q < 2; ++q) {
        float4 s = s0[q];
        unsigned int w0 = (&a0.x)[2 * q], w1 = (&a0.x)[2 * q + 1];
        acc += fmaxf((s.x + bf2f((unsigned short)w0))         * di + sb[4 * q + 0], 0.0f) * sW[4 * q + 0];
        acc += fmaxf((s.y + bf2f((unsigned short)(w0 >> 16))) * di + sb[4 * q + 1], 0.0f) * sW[4 * q + 1];
        acc += fmaxf((s.z + bf2f((unsigned short)w1))         * di + sb[4 * q + 2], 0.0f) * sW[4 * q + 2];
        acc += fmaxf((s.w + bf2f((unsigned short)(w1 >> 16))) * di + sb[4 * q + 3], 0.0f) * sW[4 * q + 3];
    }
#pragma unroll
    for (int q = 0; q < 2; ++q) {
        float4 s = s1[q];
        unsigned int w0 = (&a1.x)[2 * q], w1 = (&a1.x)[2 * q + 1];
        acc += fmaxf((s.x + bf2f((unsigned short)w0))         * di + sb[8 + 4 * q + 0], 0.0f) * sW[8 + 4 * q + 0];
        acc += fmaxf((s.y + bf2f((unsigned short)(w0 >> 16))) * di + sb[8 + 4 * q + 1], 0.0f) * sW[8 + 4 * q + 1];
        acc += fmaxf((s.z + bf2f((unsigned short)w1))         * di + sb[8 + 4 * q + 2], 0.0f) * sW[8 + 4 * q + 2];
        acc += fmaxf((s.w + bf2f((unsigned short)(w1 >> 16))) * di + sb[8 + 4 * q + 3], 0.0f) * sW[8 + 4 * q + 3];
    }
    t3[v] = acc * di;
}

// ============ final: gather t3 (scalar), bias, sigmoid ============
__global__ __launch_bounds__(256) void k_gather_final(const int* __restrict__ row_start,
                                                      const int* __restrict__ ssrc,
                                                      const float* __restrict__ t3,
                                                      const float* __restrict__ dinv,
                                                      const float* __restrict__ b_out,
                                                      float* __restrict__ out) {
    int tid = threadIdx.x;
    int v = blockIdx.x * 16 + (tid >> 4);
    int l = tid & 15;
    int e0 = row_start[v], e1 = row_start[v + 1];
    float sum = 0.0f;
    for (int e = e0 + l; e < e1; e += 16) sum += t3[ssrc[e]];
    sum += __shfl_xor(sum, 1);
    sum += __shfl_xor(sum, 2);
    sum += __shfl_xor(sum, 4);
    sum += __shfl_xor(sum, 8);
    if (l == 0) {
        float z = (sum + t3[v]) * dinv[v] + b_out[0];
        out[v] = 1.0f / (1.0f + expf(-z));
    }
}

extern "C" void kernel_launch(void* const* d_in, const int* in_sizes, int n_in,
                              void* d_out, int out_size, void* d_ws, size_t ws_size,
                              hipStream_t stream) {
    const float* x     = (const float*)d_in[0];
    const int*   ei    = (const int*)d_in[1];
    const float* W_in  = (const float*)d_in[2];
    const float* b_in  = (const float*)d_in[3];
    const float* W_mid = (const float*)d_in[4];
    const float* b_mid = (const float*)d_in[5];
    const float* W_out = (const float*)d_in[6];
    const float* b_out = (const float*)d_in[7];
    float* out = (float*)d_out;

    const int* src = ei;
    const int* dst = ei + NE;

    // workspace (~50 MB): tA/tB/t3 alias `packed` (dead after k_bucket_sort)
    char* p = (char*)d_ws;
    int*   C         = (int*)p;      p += sizeof(int) * NSCAN;
    int*   psum      = (int*)p;      p += sizeof(int) * 160;
    int*   bstart    = (int*)p;      p += sizeof(int) * (NBUCK + 2);
    int*   row_start = (int*)p;      p += sizeof(int) * (NN + 1);
    float* dinv      = (float*)p;    p += sizeof(float) * NN;
    int*   ssrc      = (int*)p;      p += sizeof(int) * (size_t)NE;   // live through gathers
    int*   packed    = (int*)p;      p += sizeof(int) * (size_t)NE;   // dead after bucket_sort
    float* sums0     = (float*)p;    p += sizeof(float) * PL;         // 4.8 MB
    float* sums1     = (float*)p;    p += sizeof(float) * PL;         // 4.8 MB
    unsigned short* tA = (unsigned short*)packed;                      // 2 planes, 4.8 MB (alias)
    unsigned short* tB = tA + 2 * PL;                                  // 2 planes, 4.8 MB (alias)
    float* t3          = (float*)(tB + 2 * PL);                        // 0.6 MB (alias)

    const int gNH = (NN * HD + 255) / 256;  // 9375
    const int gV  = NN / 16;                // 9375
    const int gN  = (NN + 255) / 256;       // 586

    // ---- build dst-bucketed CSR via two-level counting sort ----
    k_part_count<<<NBLK, 512, 0, stream>>>(dst, C);
    k_scanA<<<SCANB, 1024, 0, stream>>>(C, psum);
    k_scanB<<<1, 512, 0, stream>>>(psum);
    k_scanC<<<SCANB, 1024, 0, stream>>>(C, psum, bstart);
    k_part_scatter<<<NBLK, 512, 0, stream>>>(src, dst, C, packed);
    k_bucket_sort<<<NBUCK, 256, 0, stream>>>(packed, bstart, row_start, dinv, ssrc);

    // ---- layer 1: 3 -> 16, plane-split output ----
    k_transform_in<<<gNH, 256, 0, stream>>>(x, W_in, dinv, tA);

    // ---- layer 2: two plane gathers + finish ----
    k_gather_plane<<<gV, 512, 0, stream>>>(row_start, ssrc, tA,      sums0);
    k_gather_plane<<<gV, 512, 0, stream>>>(row_start, ssrc, tA + PL, sums1);
    k_mlp_mid<<<gN, 256, 0, stream>>>(sums0, sums1, tA, dinv, b_in, W_mid, tB);

    // ---- layer 3: two plane gathers + finish (16 -> 1) ----
    k_gather_plane<<<gV, 512, 0, stream>>>(row_start, ssrc, tB,      sums0);
    k_gather_plane<<<gV, 512, 0, stream>>>(row_start, ssrc, tB + PL, sums1);
    k_out_finish<<<gN, 256, 0, stream>>>(sums0, sums1, tB, dinv, b_mid, W_out, t3);

    // ---- final: gather t3, sigmoid ----
    k_gather_final<<<gV, 256, 0, stream>>>(row_start, ssrc, t3, dinv, b_out, out);
}